// Round 1
// baseline (31239.441 us; speedup 1.0000x reference)
//
#include <hip/hip_runtime.h>
#include <hip/hip_cooperative_groups.h>
#include <cstdint>
#include <cstddef>

namespace cg = cooperative_groups;

typedef unsigned short u16;
typedef __attribute__((ext_vector_type(8))) short short8;   // 8 x bf16 (4 VGPRs)
typedef __attribute__((ext_vector_type(4))) float f32x4;

#define MFMA16(a, b, c) __builtin_amdgcn_mfma_f32_16x16x32_bf16((a), (b), (c), 0, 0, 0)

// B=64, T=512, D=512, H=1024; M = B*T = 32768
// hi/lo bf16 split: v ~= hi + lo, residual ~2^-17 * |v| -> fp32-grade via 3 MFMA products.

static __device__ __forceinline__ u16 f2bf_rne(float f) {
  uint32_t u = __float_as_uint(f);
  u += 0x7FFFu + ((u >> 16) & 1u);
  return (u16)(u >> 16);
}
static __device__ __forceinline__ float bf2f(u16 h) {
  return __uint_as_float((uint32_t)h << 16);
}

// ---------------- prep: split fp32 array into hi/lo bf16 ----------------
__global__ void split_arr(const float* __restrict__ src, u16* __restrict__ hi,
                          u16* __restrict__ lo, int n) {
  int i = blockIdx.x * blockDim.x + threadIdx.x;
  if (i >= n) return;
  float f = src[i];
  u16 h = f2bf_rne(f);
  hi[i] = h;
  lo[i] = f2bf_rne(f - bf2f(h));
}

__global__ void bias_sum(const float* __restrict__ a, const float* __restrict__ b,
                         float* __restrict__ o) {
  int i = blockIdx.x * blockDim.x + threadIdx.x;
  if (i < 1024) o[i] = a[i] + b[i];
}

// ---------------- phase 1: xin = x @ W_in^T + bsum  -> d_out ----------------
// x: [32768, 512] fp32 (converted to hi/lo during staging); W hi/lo: [1024, 512] bf16.
// 64x64 tile per wg, 4 waves, wave w owns rows 16w..16w+15, 4 n-subtiles.
__global__ __launch_bounds__(256) void xin_gemm(
    const float* __restrict__ x, const u16* __restrict__ Bh, const u16* __restrict__ Bl,
    const float* __restrict__ bsum, float* __restrict__ out) {
  __shared__ u16 Ahi[64 * 40], Alo[64 * 40], Bhi[64 * 40], Blo[64 * 40];  // pad 32->40
  const int mb = blockIdx.y * 64, nb = blockIdx.x * 64;
  const int tid = threadIdx.x, wave = tid >> 6, lane = tid & 63;
  const int mn = lane & 15, q = lane >> 4;
  const int srow = tid >> 2, scg = tid & 3;  // staging: row 0..63, 8-float chunk 0..3

  f32x4 acc[4] = {};

  for (int kb = 0; kb < 512; kb += 32) {
    // load A chunk (fp32) + convert to hi/lo
    const float* ap = x + (size_t)(mb + srow) * 512 + kb + scg * 8;
    float4 a0 = *(const float4*)ap;
    float4 a1 = *(const float4*)(ap + 4);
    float av[8] = {a0.x, a0.y, a0.z, a0.w, a1.x, a1.y, a1.z, a1.w};
    short8 vh, vl;
#pragma unroll
    for (int j = 0; j < 8; ++j) {
      u16 h = f2bf_rne(av[j]);
      vh[j] = (short)h;
      vl[j] = (short)f2bf_rne(av[j] - bf2f(h));
    }
    const u16* bph = Bh + (size_t)(nb + srow) * 512 + kb + scg * 8;
    const u16* bpl = Bl + (size_t)(nb + srow) * 512 + kb + scg * 8;
    short8 wh = *(const short8*)bph;
    short8 wl = *(const short8*)bpl;

    __syncthreads();  // previous iter's LDS reads done
    *(short8*)&Ahi[srow * 40 + scg * 8] = vh;
    *(short8*)&Alo[srow * 40 + scg * 8] = vl;
    *(short8*)&Bhi[srow * 40 + scg * 8] = wh;
    *(short8*)&Blo[srow * 40 + scg * 8] = wl;
    __syncthreads();

    short8 ah = *(const short8*)&Ahi[(wave * 16 + mn) * 40 + q * 8];
    short8 al = *(const short8*)&Alo[(wave * 16 + mn) * 40 + q * 8];
#pragma unroll
    for (int nt = 0; nt < 4; ++nt) {
      short8 bh8 = *(const short8*)&Bhi[(nt * 16 + mn) * 40 + q * 8];
      short8 bl8 = *(const short8*)&Blo[(nt * 16 + mn) * 40 + q * 8];
      acc[nt] = MFMA16(ah, bh8, acc[nt]);
      acc[nt] = MFMA16(al, bh8, acc[nt]);
      acc[nt] = MFMA16(ah, bl8, acc[nt]);
    }
  }
  // epilogue: D[m][n]: n = lane&15, m = q*4 + reg  (m89-verified C/D layout)
#pragma unroll
  for (int nt = 0; nt < 4; ++nt) {
#pragma unroll
    for (int r = 0; r < 4; ++r) {
      int row = mb + wave * 16 + q * 4 + r;
      int col = nb + nt * 16 + mn;
      out[(size_t)row * 1024 + col] = acc[nt][r] + bsum[col];
    }
  }
}

// ---------------- phase 2: recurrence, cooperative ----------------
// grid (64, 4): blockIdx.x -> 16-col tile of H, blockIdx.y -> 16-batch tile.
// W_hh rows for this wg persistent in LDS (hi+lo, padded stride 1040).
// 4 waves split K=1024 (256 each), LDS reduce, tanh, in-place write to d_out,
// double-buffered h (hi/lo bf16) in ws. One grid.sync per step.
__global__ __launch_bounds__(256) void rnn_steps(
    const u16* __restrict__ Wh, const u16* __restrict__ Wl, u16* __restrict__ hhi,
    u16* __restrict__ hlo, float* __restrict__ io) {
  extern __shared__ __align__(16) char smem[];
  u16* Whi = (u16*)smem;                 // [16][1040] = 33280 B
  u16* Wlo = (u16*)(smem + 33280);       // [16][1040]
  float* red = (float*)(smem + 66560);   // [4][16][16] = 4096 B

  const int tid = threadIdx.x, wave = tid >> 6, lane = tid & 63;
  const int mn = lane & 15, q = lane >> 4;
  const int c0 = blockIdx.x * 16;  // output-feature base
  const int b0 = blockIdx.y * 16;  // batch base

  // persistent W tile load (16 rows x 1024, hi+lo)
  for (int it = tid; it < 16 * 128; it += 256) {
    int r = it >> 7, c = it & 127;
    *(short8*)&Whi[r * 1040 + c * 8] = *(const short8*)(Wh + (size_t)(c0 + r) * 1024 + c * 8);
    *(short8*)&Wlo[r * 1040 + c * 8] = *(const short8*)(Wl + (size_t)(c0 + r) * 1024 + c * 8);
  }
  // zero h0 (buffer 0): grid has exactly 65536 threads
  int gid = (blockIdx.y * gridDim.x + blockIdx.x) * 256 + tid;
  hhi[gid] = 0;
  hlo[gid] = 0;

  cg::grid_group grid = cg::this_grid();
  grid.sync();

  const int om = tid >> 4, on = tid & 15;
  const size_t obase = ((size_t)(b0 + om) * 512) * 1024 + (size_t)(c0 + on);
  const int hidx = (b0 + om) * 1024 + c0 + on;

  for (int t = 0; t < 512; ++t) {
    const u16* cur_hi = hhi + ((size_t)(t & 1) << 16);
    const u16* cur_lo = hlo + ((size_t)(t & 1) << 16);
    u16* nxt_hi = hhi + ((size_t)((t + 1) & 1) << 16);
    u16* nxt_lo = hlo + ((size_t)((t + 1) & 1) << 16);

    float xv = io[obase + (size_t)t * 1024];  // xin for my output element

    const u16* hrh = cur_hi + (size_t)(b0 + mn) * 1024 + wave * 256;
    const u16* hrl = cur_lo + (size_t)(b0 + mn) * 1024 + wave * 256;
    const u16* wrh = &Whi[mn * 1040 + wave * 256];
    const u16* wrl = &Wlo[mn * 1040 + wave * 256];

    f32x4 acc = {};
#pragma unroll
    for (int ch = 0; ch < 8; ++ch) {
      int k = ch * 32 + q * 8;
      short8 ah = *(const short8*)(hrh + k);
      short8 al = *(const short8*)(hrl + k);
      short8 bh8 = *(const short8*)(wrh + k);
      short8 bl8 = *(const short8*)(wrl + k);
      acc = MFMA16(ah, bh8, acc);
      acc = MFMA16(al, bh8, acc);
      acc = MFMA16(ah, bl8, acc);
    }
    // cross-wave K reduction via LDS
#pragma unroll
    for (int r = 0; r < 4; ++r) red[wave * 256 + (q * 4 + r) * 16 + mn] = acc[r];
    __syncthreads();
    float s = red[0 * 256 + om * 16 + on] + red[1 * 256 + om * 16 + on] +
              red[2 * 256 + om * 16 + on] + red[3 * 256 + om * 16 + on];
    float v = tanhf(s + xv);
    io[obase + (size_t)t * 1024] = v;  // h_t is the output at (b, t, :)
    u16 vh = f2bf_rne(v);
    nxt_hi[hidx] = vh;
    nxt_lo[hidx] = f2bf_rne(v - bf2f(vh));
    __threadfence();
    grid.sync();
  }
}

// ---------------- host ----------------
extern "C" void kernel_launch(void* const* d_in, const int* in_sizes, int n_in, void* d_out,
                              int out_size, void* d_ws, size_t ws_size, hipStream_t stream) {
  (void)in_sizes; (void)n_in; (void)out_size; (void)ws_size;
  const float* x    = (const float*)d_in[0];  // [64,512,512]
  const float* W_in = (const float*)d_in[1];  // [1024,512]
  const float* b_in = (const float*)d_in[2];  // [1024]
  const float* W_hh = (const float*)d_in[3];  // [1024,1024]
  const float* bias = (const float*)d_in[4];  // [1024]
  float* out = (float*)d_out;                 // [64,512,1024]
  char* ws = (char*)d_ws;

  u16* win_hi = (u16*)(ws);                         // 1 MB
  u16* win_lo = (u16*)(ws + (1u << 20));            // 1 MB
  u16* whh_hi = (u16*)(ws + (2u << 20));            // 2 MB
  u16* whh_lo = (u16*)(ws + (4u << 20));            // 2 MB
  float* bsum = (float*)(ws + (6u << 20));          // 4 KB
  u16* hhi    = (u16*)(ws + (6u << 20) + 65536);    // 2 x 65536 u16 = 256 KB
  u16* hlo    = (u16*)(ws + (6u << 20) + 65536 + 262144);

  split_arr<<<dim3(524288 / 256), dim3(256), 0, stream>>>(W_in, win_hi, win_lo, 524288);
  split_arr<<<dim3(1048576 / 256), dim3(256), 0, stream>>>(W_hh, whh_hi, whh_lo, 1048576);
  bias_sum<<<dim3(4), dim3(256), 0, stream>>>(b_in, bias, bsum);

  xin_gemm<<<dim3(16, 512), dim3(256), 0, stream>>>(x, win_hi, win_lo, bsum, out);

  static const unsigned kSmem = 70656;  // 2*16*1040*2 + 4096
  hipFuncSetAttribute((const void*)rnn_steps, hipFuncAttributeMaxDynamicSharedMemorySize,
                      (int)kSmem);
  void* args[5];
  args[0] = (void*)&whh_hi;
  args[1] = (void*)&whh_lo;
  args[2] = (void*)&hhi;
  args[3] = (void*)&hlo;
  args[4] = (void*)&out;
  hipLaunchCooperativeKernel((const void*)rnn_steps, dim3(64, 4), dim3(256, 1, 1), args, kSmem,
                             stream);
}

// Round 2
// 3240.987 us; speedup vs baseline: 9.6389x; 9.6389x over previous
//
#include <hip/hip_runtime.h>
#include <cstdint>
#include <cstddef>

typedef unsigned short u16;
typedef unsigned int u32;
typedef unsigned long long u64;
typedef __attribute__((ext_vector_type(8))) short short8;   // 8 x bf16
typedef __attribute__((ext_vector_type(4))) float f32x4;

#define MFMA16(a, b, c) __builtin_amdgcn_mfma_f32_16x16x32_bf16((a), (b), (c), 0, 0, 0)
#define SCOPE_AGENT __HIP_MEMORY_SCOPE_AGENT

// B=64, T=512, D=512, H=1024.
// hi/lo bf16 split everywhere: fp32-grade via 3 MFMA products (round-1 absmax 0.0039).

static __device__ __forceinline__ u16 f2bf_rne(float f) {
  uint32_t u = __float_as_uint(f);
  u += 0x7FFFu + ((u >> 16) & 1u);
  return (u16)(u >> 16);
}
static __device__ __forceinline__ float bf2f(u16 h) {
  return __uint_as_float((uint32_t)h << 16);
}

// ---------------- prep ----------------
__global__ void split_arr(const float* __restrict__ src, u16* __restrict__ hi,
                          u16* __restrict__ lo, int n) {
  int i = blockIdx.x * blockDim.x + threadIdx.x;
  if (i >= n) return;
  float f = src[i];
  u16 h = f2bf_rne(f);
  hi[i] = h;
  lo[i] = f2bf_rne(f - bf2f(h));
}

__global__ void bias_init(const float* __restrict__ a, const float* __restrict__ b,
                          float* __restrict__ o, u32* __restrict__ cnt) {
  int i = blockIdx.x * blockDim.x + threadIdx.x;
  if (i < 1024) o[i] = a[i] + b[i];
  if (i < 4)  // one padded (256B) barrier counter per batch-group, agent-visible zero
    __hip_atomic_store(cnt + i * 64, 0u, __ATOMIC_RELAXED, SCOPE_AGENT);
}

// ---------------- phase 1: xin = x @ W_in^T + bsum -> d_out (unchanged, passed R1) ----
__global__ __launch_bounds__(256) void xin_gemm(
    const float* __restrict__ x, const u16* __restrict__ Bh, const u16* __restrict__ Bl,
    const float* __restrict__ bsum, float* __restrict__ out) {
  __shared__ u16 Ahi[64 * 40], Alo[64 * 40], Bhi[64 * 40], Blo[64 * 40];
  const int mb = blockIdx.y * 64, nb = blockIdx.x * 64;
  const int tid = threadIdx.x, wave = tid >> 6, lane = tid & 63;
  const int mn = lane & 15, q = lane >> 4;
  const int srow = tid >> 2, scg = tid & 3;

  f32x4 acc[4] = {};
  for (int kb = 0; kb < 512; kb += 32) {
    const float* ap = x + (size_t)(mb + srow) * 512 + kb + scg * 8;
    float4 a0 = *(const float4*)ap;
    float4 a1 = *(const float4*)(ap + 4);
    float av[8] = {a0.x, a0.y, a0.z, a0.w, a1.x, a1.y, a1.z, a1.w};
    short8 vh, vl;
#pragma unroll
    for (int j = 0; j < 8; ++j) {
      u16 h = f2bf_rne(av[j]);
      vh[j] = (short)h;
      vl[j] = (short)f2bf_rne(av[j] - bf2f(h));
    }
    short8 wh = *(const short8*)(Bh + (size_t)(nb + srow) * 512 + kb + scg * 8);
    short8 wl = *(const short8*)(Bl + (size_t)(nb + srow) * 512 + kb + scg * 8);

    __syncthreads();
    *(short8*)&Ahi[srow * 40 + scg * 8] = vh;
    *(short8*)&Alo[srow * 40 + scg * 8] = vl;
    *(short8*)&Bhi[srow * 40 + scg * 8] = wh;
    *(short8*)&Blo[srow * 40 + scg * 8] = wl;
    __syncthreads();

    short8 ah = *(const short8*)&Ahi[(wave * 16 + mn) * 40 + q * 8];
    short8 al = *(const short8*)&Alo[(wave * 16 + mn) * 40 + q * 8];
#pragma unroll
    for (int nt = 0; nt < 4; ++nt) {
      short8 bh8 = *(const short8*)&Bhi[(nt * 16 + mn) * 40 + q * 8];
      short8 bl8 = *(const short8*)&Blo[(nt * 16 + mn) * 40 + q * 8];
      acc[nt] = MFMA16(ah, bh8, acc[nt]);
      acc[nt] = MFMA16(al, bh8, acc[nt]);
      acc[nt] = MFMA16(ah, bl8, acc[nt]);
    }
  }
#pragma unroll
  for (int nt = 0; nt < 4; ++nt)
#pragma unroll
    for (int r = 0; r < 4; ++r) {
      int row = mb + wave * 16 + q * 4 + r;
      int col = nb + nt * 16 + mn;
      out[(size_t)row * 1024 + col] = acc[nt][r] + bsum[col];
    }
}

// ---------------- phase 2: recurrence ----------------
// grid (32, 4): cg=blockIdx.x -> 32-col tile (W rows c0..c0+31 persistent in LDS, hi+lo),
// bg=blockIdx.y -> 16-batch group. Batch-groups are fully independent: private barrier
// (32 arrivals). Cross-wg h traffic via agent-scope relaxed atomics (no cache flushes).
// h packed per feature: u32 = (bf16_hi << 16) | bf16_lo. Double-buffered in ws.
__global__ __launch_bounds__(256) void rnn_steps(
    const u16* __restrict__ Wh, const u16* __restrict__ Wl, u32* hbuf, u32* cnt,
    float* __restrict__ io) {
  extern __shared__ __align__(16) char smem[];
  u16* Whi = (u16*)smem;                        // [32][1032]  66048 B
  u16* Wlo = (u16*)(smem + 66048);              // [32][1032]  66048 B
  float* red = (float*)(smem + 132096);         // [4][16][33] 8448 B

  const int tid = threadIdx.x, wave = tid >> 6, lane = tid & 63;
  const int mn = lane & 15, q = lane >> 4;
  const int cg = blockIdx.x, bg = blockIdx.y;
  const int c0 = cg * 32, b0 = bg * 16;
  u32* mycnt = cnt + bg * 64;  // 256B-padded counter per batch-group

  // persistent W tile: 32 rows x 1024, hi+lo
  for (int it = tid; it < 32 * 128; it += 256) {
    int r = it >> 7, c = it & 127;
    *(short8*)&Whi[r * 1032 + c * 8] = *(const short8*)(Wh + (size_t)(c0 + r) * 1024 + c * 8);
    *(short8*)&Wlo[r * 1032 + c * 8] = *(const short8*)(Wl + (size_t)(c0 + r) * 1024 + c * 8);
  }

  // zero h0 slice (buffer 0): my (16 batches x 32 cols) = 512 u32 = 256 u64
  {
    u64* hz = (u64*)(hbuf) + ((size_t)b0 * 1024 + c0) / 2;
    for (int i = tid; i < 256; i += 256) {
      int b = i >> 4, cpair = i & 15;
      __hip_atomic_store(hz + b * 512 + cpair, 0ull, __ATOMIC_RELAXED, SCOPE_AGENT);
    }
  }
  asm volatile("s_waitcnt vmcnt(0)" ::: "memory");
  __syncthreads();
  if (tid == 0) {
    __hip_atomic_fetch_add(mycnt, 1u, __ATOMIC_RELAXED, SCOPE_AGENT);
    while (__hip_atomic_load(mycnt, __ATOMIC_RELAXED, SCOPE_AGENT) < 32u)
      __builtin_amdgcn_s_sleep(1);
  }
  __syncthreads();

  // output ownership: 256 threads -> 16 batches x 32 cols, 2 cols/thread
  const int om = tid >> 4, on2 = (tid & 15) * 2;
  const size_t iobase = ((size_t)(b0 + om) * 512) * 1024 + c0 + on2;
  float2 xv = *(const float2*)(io + iobase);  // t=0

  for (int t = 0; t < 512; ++t) {
    const u32* cur = hbuf + ((size_t)(t & 1) << 16);
    u32* nxt = hbuf + ((size_t)((t + 1) & 1) << 16);

    f32x4 acc[2] = {};  // [nt]
    const int kbase = wave * 256;
#pragma unroll
    for (int kt = 0; kt < 8; ++kt) {
      const int k = kbase + kt * 32 + q * 8;
      // A-frag: h row (b0+mn), 8 consecutive packed features via 4 agent u64 loads
      short8 ah, al;
      {
        const u64* p = (const u64*)(cur + (size_t)(b0 + mn) * 1024 + k);
#pragma unroll
        for (int i = 0; i < 4; ++i) {
          u64 d = __hip_atomic_load(p + i, __ATOMIC_RELAXED, SCOPE_AGENT);
          u32 w0 = (u32)d, w1 = (u32)(d >> 32);
          ah[2 * i]     = (short)(w0 >> 16);
          al[2 * i]     = (short)(w0 & 0xffffu);
          ah[2 * i + 1] = (short)(w1 >> 16);
          al[2 * i + 1] = (short)(w1 & 0xffffu);
        }
      }
#pragma unroll
      for (int nt = 0; nt < 2; ++nt) {
        short8 bh = *(const short8*)&Whi[(nt * 16 + mn) * 1032 + k];
        short8 bl = *(const short8*)&Wlo[(nt * 16 + mn) * 1032 + k];
        acc[nt] = MFMA16(ah, bh, acc[nt]);
        acc[nt] = MFMA16(al, bh, acc[nt]);
        acc[nt] = MFMA16(ah, bl, acc[nt]);
      }
    }
    // cross-wave K-reduction partials: red[wave][m=q*4+r][col=nt*16+mn], m-stride 33
#pragma unroll
    for (int nt = 0; nt < 2; ++nt)
#pragma unroll
      for (int r = 0; r < 4; ++r)
        red[wave * 528 + (q * 4 + r) * 33 + nt * 16 + mn] = acc[nt][r];

    float2 xv_next;
    if (t < 511) xv_next = *(const float2*)(io + iobase + (size_t)(t + 1) * 1024);
    __syncthreads();

    float o0, o1;
    {
      float s0 = 0.f, s1 = 0.f;
#pragma unroll
      for (int w = 0; w < 4; ++w) {
        s0 += red[w * 528 + om * 33 + on2];
        s1 += red[w * 528 + om * 33 + on2 + 1];
      }
      o0 = tanhf(s0 + xv.x);
      o1 = tanhf(s1 + xv.y);
    }
    *(float2*)(io + iobase + (size_t)t * 1024) = make_float2(o0, o1);  // h_t -> output

    u16 h0 = f2bf_rne(o0), h1 = f2bf_rne(o1);
    u32 p0 = ((u32)h0 << 16) | f2bf_rne(o0 - bf2f(h0));
    u32 p1 = ((u32)h1 << 16) | f2bf_rne(o1 - bf2f(h1));
    u64* hp = (u64*)(nxt + (size_t)(b0 + om) * 1024 + c0 + on2);
    __hip_atomic_store(hp, ((u64)p1 << 32) | p0, __ATOMIC_RELAXED, SCOPE_AGENT);

    if (t < 511) {
      asm volatile("s_waitcnt vmcnt(0)" ::: "memory");  // h stores at coherent point
      __syncthreads();
      if (tid == 0) {
        __hip_atomic_fetch_add(mycnt, 1u, __ATOMIC_RELAXED, SCOPE_AGENT);
        const u32 tg = 32u * (u32)(t + 2);
        while (__hip_atomic_load(mycnt, __ATOMIC_RELAXED, SCOPE_AGENT) < tg)
          __builtin_amdgcn_s_sleep(1);
      }
      __syncthreads();
    }
    xv = xv_next;
  }
}

// ---------------- host ----------------
extern "C" void kernel_launch(void* const* d_in, const int* in_sizes, int n_in, void* d_out,
                              int out_size, void* d_ws, size_t ws_size, hipStream_t stream) {
  (void)in_sizes; (void)n_in; (void)out_size; (void)ws_size;
  const float* x    = (const float*)d_in[0];
  const float* W_in = (const float*)d_in[1];
  const float* b_in = (const float*)d_in[2];
  const float* W_hh = (const float*)d_in[3];
  const float* bias = (const float*)d_in[4];
  float* out = (float*)d_out;
  char* ws = (char*)d_ws;

  u16* win_hi = (u16*)(ws);
  u16* win_lo = (u16*)(ws + (1u << 20));
  u16* whh_hi = (u16*)(ws + (2u << 20));
  u16* whh_lo = (u16*)(ws + (4u << 20));
  float* bsum = (float*)(ws + (6u << 20));
  u32* hbuf   = (u32*)(ws + (6u << 20) + 65536);              // 2 x 64*1024 u32 = 512 KB
  u32* cnt    = (u32*)(ws + (6u << 20) + 65536 + 524288);     // 4 x 256B padded counters

  split_arr<<<dim3(524288 / 256), dim3(256), 0, stream>>>(W_in, win_hi, win_lo, 524288);
  split_arr<<<dim3(1048576 / 256), dim3(256), 0, stream>>>(W_hh, whh_hi, whh_lo, 1048576);
  bias_init<<<dim3(4), dim3(256), 0, stream>>>(b_in, bias, bsum, cnt);

  xin_gemm<<<dim3(16, 512), dim3(256), 0, stream>>>(x, win_hi, win_lo, bsum, out);

  static const unsigned kSmem = 140544;  // 2*66048 + 8448
  hipFuncSetAttribute((const void*)rnn_steps, hipFuncAttributeMaxDynamicSharedMemorySize,
                      (int)kSmem);
  void* args[5];
  args[0] = (void*)&whh_hi;
  args[1] = (void*)&whh_lo;
  args[2] = (void*)&hbuf;
  args[3] = (void*)&cnt;
  args[4] = (void*)&out;
  hipLaunchCooperativeKernel((const void*)rnn_steps, dim3(32, 4), dim3(256, 1, 1), args, kSmem,
                             stream);
}